// Round 1
// baseline (877.521 us; speedup 1.0000x reference)
//
#include <hip/hip_runtime.h>

#define SEQ 2048
#define NHEAD 16
#define NHID 1024

typedef __attribute__((ext_vector_type(8))) short bf16x8;
typedef __attribute__((ext_vector_type(4))) float f32x4;
typedef unsigned short u16;

__device__ inline u16 f2bf(float f) {
    union { float f; unsigned u; } v; v.f = f;
    unsigned r = v.u + 0x7FFFu + ((v.u >> 16) & 1u);
    return (u16)(r >> 16);
}

// ---------------- cast x (fp32 -> bf16), vectorized ----------------
__global__ void cast_kernel(const float* __restrict__ in, u16* __restrict__ out, int n4) {
    int i = blockIdx.x * 256 + threadIdx.x;
    if (i < n4) {
        float4 v = ((const float4*)in)[i];
        ushort4 o;
        o.x = f2bf(v.x); o.y = f2bf(v.y); o.z = f2bf(v.z); o.w = f2bf(v.w);
        ((ushort4*)out)[i] = o;
    }
}

// ---------------- transpose + cast: in (R x C) fp32 -> out (C x R) bf16 ----------------
__global__ void transpose_cast(const float* __restrict__ in, u16* __restrict__ out, int R, int C) {
    __shared__ float tile[32][33];
    int bx = blockIdx.x * 32, by = blockIdx.y * 32;
    int tx = threadIdx.x & 31, ty = threadIdx.x >> 5;
#pragma unroll
    for (int i = ty; i < 32; i += 8) tile[i][tx] = in[(size_t)(by + i) * C + bx + tx];
    __syncthreads();
#pragma unroll
    for (int i = ty; i < 32; i += 8) out[(size_t)(bx + i) * R + by + tx] = f2bf(tile[tx][i]);
}

// ---------------- GEMM1: qkv = x_bf @ Wqkv, epilogue scatters q/k/v ----------------
// A: (4096 x 1024) bf16 row-major. Bt: (3072 x 1024) bf16 (W^T). grid (24, 32)
__launch_bounds__(256, 2)
__global__ void gemm_qkv(const u16* __restrict__ A, const u16* __restrict__ Bt,
                         const float* __restrict__ bias,
                         u16* __restrict__ qs, u16* __restrict__ ks, u16* __restrict__ vs) {
    __shared__ __align__(16) u16 Alds[128 * 72];
    __shared__ __align__(16) u16 Blds[128 * 72];
    const int tid = threadIdx.x;
    const int m0 = blockIdx.y * 128, n0 = blockIdx.x * 128;
    const int lane = tid & 63, wid = tid >> 6;
    const int wm = (wid & 1) * 64, wn = (wid >> 1) * 64;
    const int col = lane & 15, quad = lane >> 4;
    const int sr = tid >> 3, scg = (tid & 7) * 8;
    f32x4 acc[4][4] = {};
    for (int k0 = 0; k0 < 1024; k0 += 64) {
#pragma unroll
        for (int p = 0; p < 4; p++) {
            int r = sr + p * 32;
            *(bf16x8*)&Alds[r * 72 + scg] = *(const bf16x8*)&A[(size_t)(m0 + r) * 1024 + k0 + scg];
            *(bf16x8*)&Blds[r * 72 + scg] = *(const bf16x8*)&Bt[(size_t)(n0 + r) * 1024 + k0 + scg];
        }
        __syncthreads();
#pragma unroll
        for (int kc = 0; kc < 2; kc++) {
            bf16x8 af[4], bfr[4];
#pragma unroll
            for (int t = 0; t < 4; t++) {
                af[t]  = *(const bf16x8*)&Alds[(wm + t * 16 + col) * 72 + kc * 32 + quad * 8];
                bfr[t] = *(const bf16x8*)&Blds[(wn + t * 16 + col) * 72 + kc * 32 + quad * 8];
            }
#pragma unroll
            for (int mt = 0; mt < 4; mt++)
#pragma unroll
                for (int nt = 0; nt < 4; nt++)
                    acc[mt][nt] = __builtin_amdgcn_mfma_f32_16x16x32_bf16(af[mt], bfr[nt], acc[mt][nt], 0, 0, 0);
        }
        __syncthreads();
    }
#pragma unroll
    for (int mt = 0; mt < 4; mt++)
#pragma unroll
        for (int nt = 0; nt < 4; nt++)
#pragma unroll
            for (int r = 0; r < 4; r++) {
                int gm = m0 + wm + mt * 16 + quad * 4 + r;
                int gn = n0 + wn + nt * 16 + col;
                float val = acc[mt][nt][r] + bias[gn];
                int b = gm >> 11, s = gm & 2047;
                int h = gn / 192, rr = gn - h * 192;
                size_t base = ((size_t)(b * NHEAD + h) * SEQ + s) * 64;
                if (rr < 64)        qs[base + rr] = f2bf(val * 0.125f);   // pre-scale by 1/sqrt(64)
                else if (rr < 128)  ks[base + rr - 64] = f2bf(val);
                else                vs[base + rr - 128] = f2bf(val);
            }
}

// ---------------- flash attention: grid (32 qtiles, 32 bh), 256 thr ----------------
__launch_bounds__(256, 2)
__global__ void attn_kernel(const u16* __restrict__ qs, const u16* __restrict__ ks,
                            const u16* __restrict__ vs, const int* __restrict__ mask,
                            u16* __restrict__ ctx) {
    __shared__ __align__(16) u16 Klds[64 * 72];
    __shared__ __align__(16) u16 Vt[64 * 72];
    __shared__ __align__(16) u16 Plds[4][16 * 72];
    const int tid = threadIdx.x;
    const int lane = tid & 63, wid = tid >> 6;
    const int col = lane & 15, quad = lane >> 4;
    const int bh = blockIdx.y;
    const int b = bh >> 4, h = bh & 15;
    const int q0 = blockIdx.x * 64;
    const size_t hbase = (size_t)bh * SEQ * 64;

    // Q fragments (A-operand layout: m=lane&15, k=quad*8+j), wave owns 16 q-rows
    const u16* qp = qs + hbase + (size_t)(q0 + wid * 16 + col) * 64 + quad * 8;
    bf16x8 aq0 = *(const bf16x8*)qp;
    bf16x8 aq1 = *(const bf16x8*)(qp + 32);

    float m_i[4], l_i[4], alpha[4];
    f32x4 O[4] = {};
#pragma unroll
    for (int r = 0; r < 4; r++) { m_i[r] = -INFINITY; l_i[r] = 0.f; }

    const int sr = tid >> 3, scg = (tid & 7) * 8;
    for (int kb = 0; kb < SEQ; kb += 64) {
        __syncthreads();   // previous PV reads done before restaging
#pragma unroll
        for (int p = 0; p < 2; p++) {
            int r = sr + p * 32;
            *(bf16x8*)&Klds[r * 72 + scg] = *(const bf16x8*)&ks[hbase + (size_t)(kb + r) * 64 + scg];
            bf16x8 vv = *(const bf16x8*)&vs[hbase + (size_t)(kb + r) * 64 + scg];
#pragma unroll
            for (int j = 0; j < 8; j++) Vt[(scg + j) * 72 + r] = (u16)vv[j];   // transpose V
        }
        __syncthreads();

        // S = Q K^T  (16 q-rows x 64 keys per wave)
        f32x4 sacc[4];
#pragma unroll
        for (int nt = 0; nt < 4; nt++) {
            bf16x8 b0 = *(const bf16x8*)&Klds[(nt * 16 + col) * 72 + quad * 8];
            bf16x8 b1 = *(const bf16x8*)&Klds[(nt * 16 + col) * 72 + 32 + quad * 8];
            f32x4 z = {};
            z = __builtin_amdgcn_mfma_f32_16x16x32_bf16(aq0, b0, z, 0, 0, 0);
            z = __builtin_amdgcn_mfma_f32_16x16x32_bf16(aq1, b1, z, 0, 0, 0);
            sacc[nt] = z;
        }
        // mask (bhqk = mask[b, q, h, k])
        float sv[4][4];
#pragma unroll
        for (int nt = 0; nt < 4; nt++)
#pragma unroll
            for (int r = 0; r < 4; r++) {
                int q = q0 + wid * 16 + quad * 4 + r;
                int key = kb + nt * 16 + col;
                int mv = mask[(((size_t)b * SEQ + q) * NHEAD + h) * SEQ + key];
                sv[nt][r] = mv ? sacc[nt][r] : -1e30f;
            }
        // online softmax (rows live on the 16 lanes of each quad)
#pragma unroll
        for (int r = 0; r < 4; r++) {
            float rm = fmaxf(fmaxf(sv[0][r], sv[1][r]), fmaxf(sv[2][r], sv[3][r]));
            rm = fmaxf(rm, __shfl_xor(rm, 1));
            rm = fmaxf(rm, __shfl_xor(rm, 2));
            rm = fmaxf(rm, __shfl_xor(rm, 4));
            rm = fmaxf(rm, __shfl_xor(rm, 8));
            float mnew = fmaxf(m_i[r], rm);
            alpha[r] = __expf(m_i[r] - mnew);
            m_i[r] = mnew;
        }
        float rsum[4] = {0.f, 0.f, 0.f, 0.f};
#pragma unroll
        for (int nt = 0; nt < 4; nt++)
#pragma unroll
            for (int r = 0; r < 4; r++) {
                float p = __expf(sv[nt][r] - m_i[r]);
                rsum[r] += p;
                Plds[wid][(quad * 4 + r) * 72 + nt * 16 + col] = f2bf(p);
            }
#pragma unroll
        for (int r = 0; r < 4; r++) {
            float rs = rsum[r];
            rs += __shfl_xor(rs, 1);
            rs += __shfl_xor(rs, 2);
            rs += __shfl_xor(rs, 4);
            rs += __shfl_xor(rs, 8);
            l_i[r] = l_i[r] * alpha[r] + rs;
        }
#pragma unroll
        for (int dt = 0; dt < 4; dt++)
#pragma unroll
            for (int r = 0; r < 4; r++) O[dt][r] *= alpha[r];
        __syncthreads();   // P visible for A-operand reads

        // O += P V   (P via LDS round-trip: C-layout -> A-layout)
        bf16x8 ap0 = *(const bf16x8*)&Plds[wid][col * 72 + quad * 8];
        bf16x8 ap1 = *(const bf16x8*)&Plds[wid][col * 72 + 32 + quad * 8];
#pragma unroll
        for (int dt = 0; dt < 4; dt++) {
            bf16x8 bv0 = *(const bf16x8*)&Vt[(dt * 16 + col) * 72 + quad * 8];
            bf16x8 bv1 = *(const bf16x8*)&Vt[(dt * 16 + col) * 72 + 32 + quad * 8];
            O[dt] = __builtin_amdgcn_mfma_f32_16x16x32_bf16(ap0, bv0, O[dt], 0, 0, 0);
            O[dt] = __builtin_amdgcn_mfma_f32_16x16x32_bf16(ap1, bv1, O[dt], 0, 0, 0);
        }
    }
    // epilogue: ctx[b, q, h*64 + d] bf16
#pragma unroll
    for (int dt = 0; dt < 4; dt++)
#pragma unroll
        for (int r = 0; r < 4; r++) {
            float val = O[dt][r] / l_i[r];
            int q = q0 + wid * 16 + quad * 4 + r;
            int c = h * 64 + dt * 16 + col;
            ctx[(size_t)(b * SEQ + q) * NHID + c] = f2bf(val);
        }
}

// ---------------- GEMM2: out = ctx @ Wout + b_out + x  (fp32 out) ----------------
// A: (4096 x 1024) bf16. Bt: (1024 x 1024) bf16 (W^T). grid (8, 32)
__launch_bounds__(256, 2)
__global__ void gemm_out(const u16* __restrict__ A, const u16* __restrict__ Bt,
                         const float* __restrict__ bias, const float* __restrict__ xres,
                         float* __restrict__ out) {
    __shared__ __align__(16) u16 Alds[128 * 72];
    __shared__ __align__(16) u16 Blds[128 * 72];
    const int tid = threadIdx.x;
    const int m0 = blockIdx.y * 128, n0 = blockIdx.x * 128;
    const int lane = tid & 63, wid = tid >> 6;
    const int wm = (wid & 1) * 64, wn = (wid >> 1) * 64;
    const int col = lane & 15, quad = lane >> 4;
    const int sr = tid >> 3, scg = (tid & 7) * 8;
    f32x4 acc[4][4] = {};
    for (int k0 = 0; k0 < 1024; k0 += 64) {
#pragma unroll
        for (int p = 0; p < 4; p++) {
            int r = sr + p * 32;
            *(bf16x8*)&Alds[r * 72 + scg] = *(const bf16x8*)&A[(size_t)(m0 + r) * 1024 + k0 + scg];
            *(bf16x8*)&Blds[r * 72 + scg] = *(const bf16x8*)&Bt[(size_t)(n0 + r) * 1024 + k0 + scg];
        }
        __syncthreads();
#pragma unroll
        for (int kc = 0; kc < 2; kc++) {
            bf16x8 af[4], bfr[4];
#pragma unroll
            for (int t = 0; t < 4; t++) {
                af[t]  = *(const bf16x8*)&Alds[(wm + t * 16 + col) * 72 + kc * 32 + quad * 8];
                bfr[t] = *(const bf16x8*)&Blds[(wn + t * 16 + col) * 72 + kc * 32 + quad * 8];
            }
#pragma unroll
            for (int mt = 0; mt < 4; mt++)
#pragma unroll
                for (int nt = 0; nt < 4; nt++)
                    acc[mt][nt] = __builtin_amdgcn_mfma_f32_16x16x32_bf16(af[mt], bfr[nt], acc[mt][nt], 0, 0, 0);
        }
        __syncthreads();
    }
#pragma unroll
    for (int mt = 0; mt < 4; mt++)
#pragma unroll
        for (int nt = 0; nt < 4; nt++)
#pragma unroll
            for (int r = 0; r < 4; r++) {
                int gm = m0 + wm + mt * 16 + quad * 4 + r;
                int gn = n0 + wn + nt * 16 + col;
                out[(size_t)gm * NHID + gn] = acc[mt][nt][r] + bias[gn] + xres[(size_t)gm * NHID + gn];
            }
}

extern "C" void kernel_launch(void* const* d_in, const int* in_sizes, int n_in,
                              void* d_out, int out_size, void* d_ws, size_t ws_size,
                              hipStream_t stream) {
    const float* x     = (const float*)d_in[0];
    const int*   mask  = (const int*)d_in[1];
    const float* W_qkv = (const float*)d_in[2];
    const float* b_qkv = (const float*)d_in[3];
    const float* W_out = (const float*)d_in[4];
    const float* b_out = (const float*)d_in[5];
    float* out = (float*)d_out;

    char* ws = (char*)d_ws;
    u16* x_bf   = (u16*)(ws);                    // 4096*1024*2 = 8 MB
    u16* wqkv_t = (u16*)(ws + (size_t)(8  << 20));   // 3072*1024*2 = 6 MB
    u16* wout_t = (u16*)(ws + (size_t)(14 << 20));   // 1024*1024*2 = 2 MB
    u16* qs     = (u16*)(ws + (size_t)(16 << 20));   // 8 MB
    u16* ks     = (u16*)(ws + (size_t)(24 << 20));   // 8 MB
    u16* vs     = (u16*)(ws + (size_t)(32 << 20));   // 8 MB
    u16* ctx    = (u16*)(ws + (size_t)(40 << 20));   // 8 MB  (total 48 MB)

    cast_kernel<<<4096, 256, 0, stream>>>(x, x_bf, 4096 * 1024 / 4);
    transpose_cast<<<dim3(3072 / 32, 1024 / 32), 256, 0, stream>>>(W_qkv, wqkv_t, 1024, 3072);
    transpose_cast<<<dim3(1024 / 32, 1024 / 32), 256, 0, stream>>>(W_out, wout_t, 1024, 1024);
    gemm_qkv<<<dim3(24, 32), 256, 0, stream>>>(x_bf, wqkv_t, b_qkv, qs, ks, vs);
    attn_kernel<<<dim3(32, 32), 256, 0, stream>>>(qs, ks, vs, mask, ctx);
    gemm_out<<<dim3(8, 32), 256, 0, stream>>>(ctx, wout_t, b_out, x, out);
}